// Round 5
// baseline (25.228 us; speedup 1.0000x reference)
//
#include <hip/hip_runtime.h>

// out[i*1536 + j] = -(1/0.924458) * sum_{a,b} w[a][b] * x[3i+a][3j+b]
// x: 4608x4608 f32, w: 3x3 f32, out: 1536x1536 f32.
//
// v0 structure (best so far, 19.08 us) + non-temporal loads/stores:
// x is read exactly once and out written exactly once -> bypass cache
// allocation on both streams (MUBUF nt/sc bits via
// __builtin_nontemporal_load/store).

typedef float v4f __attribute__((ext_vector_type(4)));

constexpr int W  = 4608;   // input row stride (floats)
constexpr int NH = 1536;   // output cols
constexpr int JQ = NH / 4; // 384 quads per output row

__global__ __launch_bounds__(256) void conv3x3_s3_nt(
    const float* __restrict__ x,
    const float* __restrict__ w,
    float* __restrict__ out)
{
    const int tid = blockIdx.x * blockDim.x + threadIdx.x;
    const int i   = tid / JQ;       // output row [0, 1536)
    const int jq  = tid - i * JQ;   // quad index [0, 384)

    const float w00 = w[0], w01 = w[1], w02 = w[2];
    const float w10 = w[3], w11 = w[4], w12 = w[5];
    const float w20 = w[6], w21 = w[7], w22 = w[8];

    const float* base = x + (size_t)(3 * i) * W + 12 * jq;

    float acc0 = 0.f, acc1 = 0.f, acc2 = 0.f, acc3 = 0.f;

    #pragma unroll
    for (int a = 0; a < 3; ++a) {
        const v4f* p = reinterpret_cast<const v4f*>(base + (size_t)a * W);
        const v4f v0 = __builtin_nontemporal_load(p + 0);
        const v4f v1 = __builtin_nontemporal_load(p + 1);
        const v4f v2 = __builtin_nontemporal_load(p + 2);

        float wa0, wa1, wa2;
        if (a == 0)      { wa0 = w00; wa1 = w01; wa2 = w02; }
        else if (a == 1) { wa0 = w10; wa1 = w11; wa2 = w12; }
        else             { wa0 = w20; wa1 = w21; wa2 = w22; }

        acc0 += wa0 * v0[0] + wa1 * v0[1] + wa2 * v0[2];
        acc1 += wa0 * v0[3] + wa1 * v1[0] + wa2 * v1[1];
        acc2 += wa0 * v1[2] + wa1 * v1[3] + wa2 * v2[0];
        acc3 += wa0 * v2[1] + wa1 * v2[2] + wa2 * v2[3];
    }

    const float scale = -1.0f / 0.924458f;

    v4f r;
    r[0] = acc0 * scale;
    r[1] = acc1 * scale;
    r[2] = acc2 * scale;
    r[3] = acc3 * scale;

    v4f* o = reinterpret_cast<v4f*>(out + (size_t)i * NH + 4 * jq);
    __builtin_nontemporal_store(r, o);
}

extern "C" void kernel_launch(void* const* d_in, const int* in_sizes, int n_in,
                              void* d_out, int out_size, void* d_ws, size_t ws_size,
                              hipStream_t stream)
{
    const float* x = (const float*)d_in[0];   // 4608*4608
    const float* w = (const float*)d_in[1];   // 9
    float* out = (float*)d_out;               // 1536*1536

    constexpr int total = NH * JQ;            // 589824 threads
    constexpr int block = 256;
    constexpr int grid  = total / block;      // 2304 blocks, exact

    conv3x3_s3_nt<<<grid, block, 0, stream>>>(x, w, out);
}

// Round 6
// 18.748 us; speedup vs baseline: 1.3456x; 1.3456x over previous
//
#include <hip/hip_runtime.h>

// out[i*1536 + j] = -(1/0.924458) * sum_{a,b} w[a][b] * x[3i+a][3j+b]
// x: 4608x4608 f32, w: 3x3 f32, out: 1536x1536 f32.
//
// v0 body (best: 19.08 us) + bijective XCD-aware blockIdx swizzle (T1):
// 2304 blocks % 8 XCDs == 0 -> remap so each XCD streams one contiguous
// 1/8 slab of x (288 blocks), instead of the default fine round-robin
// interleave. Tests DRAM-page / L2-channel locality as the last lever.

constexpr int W     = 4608;   // input row stride (floats)
constexpr int NH    = 1536;   // output cols
constexpr int JQ    = NH / 4; // 384 quads per output row
constexpr int GRID  = (NH * JQ) / 256;  // 2304
constexpr int NXCD  = 8;
constexpr int CPX   = GRID / NXCD;      // 288 blocks per XCD slab

__global__ __launch_bounds__(256) void conv3x3_s3_xcd(
    const float* __restrict__ x,
    const float* __restrict__ w,
    float* __restrict__ out)
{
    // Dispatcher assigns consecutive blockIdx round-robin across XCDs.
    // Remap: XCD k = blockIdx.x % 8 gets the contiguous slab
    // [k*CPX, (k+1)*CPX) of logical block ids.  Bijective since GRID%8==0.
    const int bid = (blockIdx.x % NXCD) * CPX + blockIdx.x / NXCD;

    const int tid = bid * 256 + threadIdx.x;
    const int i   = tid / JQ;       // output row [0, 1536)
    const int jq  = tid - i * JQ;   // quad index [0, 384)

    const float w00 = w[0], w01 = w[1], w02 = w[2];
    const float w10 = w[3], w11 = w[4], w12 = w[5];
    const float w20 = w[6], w21 = w[7], w22 = w[8];

    const float* base = x + (size_t)(3 * i) * W + 12 * jq;

    float acc0 = 0.f, acc1 = 0.f, acc2 = 0.f, acc3 = 0.f;

    #pragma unroll
    for (int a = 0; a < 3; ++a) {
        const float4* p = reinterpret_cast<const float4*>(base + (size_t)a * W);
        const float4 v0 = p[0];
        const float4 v1 = p[1];
        const float4 v2 = p[2];

        float wa0, wa1, wa2;
        if (a == 0)      { wa0 = w00; wa1 = w01; wa2 = w02; }
        else if (a == 1) { wa0 = w10; wa1 = w11; wa2 = w12; }
        else             { wa0 = w20; wa1 = w21; wa2 = w22; }

        acc0 += wa0 * v0.x + wa1 * v0.y + wa2 * v0.z;
        acc1 += wa0 * v0.w + wa1 * v1.x + wa2 * v1.y;
        acc2 += wa0 * v1.z + wa1 * v1.w + wa2 * v2.x;
        acc3 += wa0 * v2.y + wa1 * v2.z + wa2 * v2.w;
    }

    const float scale = -1.0f / 0.924458f;

    float4 r;
    r.x = acc0 * scale;
    r.y = acc1 * scale;
    r.z = acc2 * scale;
    r.w = acc3 * scale;

    float4* o = reinterpret_cast<float4*>(out + (size_t)i * NH + 4 * jq);
    *o = r;
}

extern "C" void kernel_launch(void* const* d_in, const int* in_sizes, int n_in,
                              void* d_out, int out_size, void* d_ws, size_t ws_size,
                              hipStream_t stream)
{
    const float* x = (const float*)d_in[0];   // 4608*4608
    const float* w = (const float*)d_in[1];   // 9
    float* out = (float*)d_out;               // 1536*1536

    conv3x3_s3_xcd<<<GRID, 256, 0, stream>>>(x, w, out);
}

// Round 7
// 18.725 us; speedup vs baseline: 1.3472x; 1.0012x over previous
//
#include <hip/hip_runtime.h>

// out[i*1536 + j] = -(1/0.924458) * sum_{a,b} w[a][b] * x[3i+a][3j+b]
// x: 4608x4608 f32, w: 3x3 f32, out: 1536x1536 f32.
//
// v6 (best: 18.75 us = v0 body + bijective XCD swizzle) + NON-TEMPORAL
// STORE ONLY. Round 5 showed NT loads kill the L1 line-merging the
// stride-48B read pattern needs (-32%); this isolates the store-stream
// cache policy: out is written once and never re-read, so bypass L2/L3
// allocation on the write stream while keeping cached reads.

typedef float v4f __attribute__((ext_vector_type(4)));

constexpr int W     = 4608;   // input row stride (floats)
constexpr int NH    = 1536;   // output cols
constexpr int JQ    = NH / 4; // 384 quads per output row
constexpr int GRID  = (NH * JQ) / 256;  // 2304
constexpr int NXCD  = 8;
constexpr int CPX   = GRID / NXCD;      // 288 blocks per XCD slab

__global__ __launch_bounds__(256) void conv3x3_s3_ntst(
    const float* __restrict__ x,
    const float* __restrict__ w,
    float* __restrict__ out)
{
    // Bijective XCD-contiguous remap (GRID % 8 == 0).
    const int bid = (blockIdx.x % NXCD) * CPX + blockIdx.x / NXCD;

    const int tid = bid * 256 + threadIdx.x;
    const int i   = tid / JQ;       // output row [0, 1536)
    const int jq  = tid - i * JQ;   // quad index [0, 384)

    const float w00 = w[0], w01 = w[1], w02 = w[2];
    const float w10 = w[3], w11 = w[4], w12 = w[5];
    const float w20 = w[6], w21 = w[7], w22 = w[8];

    const float* base = x + (size_t)(3 * i) * W + 12 * jq;

    float acc0 = 0.f, acc1 = 0.f, acc2 = 0.f, acc3 = 0.f;

    #pragma unroll
    for (int a = 0; a < 3; ++a) {
        const float4* p = reinterpret_cast<const float4*>(base + (size_t)a * W);
        const float4 v0 = p[0];   // cached loads (NT loads regress -32%)
        const float4 v1 = p[1];
        const float4 v2 = p[2];

        float wa0, wa1, wa2;
        if (a == 0)      { wa0 = w00; wa1 = w01; wa2 = w02; }
        else if (a == 1) { wa0 = w10; wa1 = w11; wa2 = w12; }
        else             { wa0 = w20; wa1 = w21; wa2 = w22; }

        acc0 += wa0 * v0.x + wa1 * v0.y + wa2 * v0.z;
        acc1 += wa0 * v0.w + wa1 * v1.x + wa2 * v1.y;
        acc2 += wa0 * v1.z + wa1 * v1.w + wa2 * v2.x;
        acc3 += wa0 * v2.y + wa1 * v2.z + wa2 * v2.w;
    }

    const float scale = -1.0f / 0.924458f;

    v4f r;
    r[0] = acc0 * scale;
    r[1] = acc1 * scale;
    r[2] = acc2 * scale;
    r[3] = acc3 * scale;

    v4f* o = reinterpret_cast<v4f*>(out + (size_t)i * NH + 4 * jq);
    __builtin_nontemporal_store(r, o);   // write-around: never re-read
}

extern "C" void kernel_launch(void* const* d_in, const int* in_sizes, int n_in,
                              void* d_out, int out_size, void* d_ws, size_t ws_size,
                              hipStream_t stream)
{
    const float* x = (const float*)d_in[0];   // 4608*4608
    const float* w = (const float*)d_in[1];   // 9
    float* out = (float*)d_out;               // 1536*1536

    conv3x3_s3_ntst<<<GRID, 256, 0, stream>>>(x, w, out);
}